// Round 12
// baseline (3484.828 us; speedup 1.0000x reference)
//
#include <hip/hip_runtime.h>
#include <hip/hip_bf16.h>
#include <stdint.h>

#define BATCH 32
#define SEQT  512
#define DIM   256
#define UU    512
#define SENT  0x7FC07FC0u   // bf16 NaN pair: finite h/x data can never equal this

typedef __attribute__((ext_vector_type(8))) short bf16x8;
typedef __attribute__((ext_vector_type(4))) float f32x4;
typedef __attribute__((ext_vector_type(4))) unsigned int u32x4;

__device__ __forceinline__ short f2bf(float f) {
  uint32_t u = __builtin_bit_cast(uint32_t, f);
  u += 0x7FFFu + ((u >> 16) & 1u);   // RNE; finite in -> finite out (never NaN)
  return (short)(u >> 16);
}
__device__ __forceinline__ uint32_t pack2(float a, float b) {
  return ((uint32_t)(uint16_t)f2bf(b) << 16) | (uint16_t)f2bf(a);
}
__device__ __forceinline__ float sigm(float x) { return 1.0f / (1.0f + __expf(-x)); }
__device__ __forceinline__ float tanh_fast(float x) {
  float ax = fabsf(x);
  float t = __expf(-2.0f * ax);
  float r = (1.0f - t) / (1.0f + t);
  return copysignf(r, x);
}

// write-through stores (visible at LLC); fire-and-forget
__device__ __forceinline__ void st4_wt(void* p, uint32_t v) {
  asm volatile("global_store_dword %0, %1, off sc0 sc1" :: "v"(p), "v"(v) : "memory");
}
__device__ __forceinline__ void st16_wt(void* p, u32x4 v) {
  asm volatile("global_store_dwordx4 %0, %1, off sc0 sc1" :: "v"(p), "v"(v) : "memory");
}

// 16x 16B LLC-coherent loads + waitcnt inside one asm block (r9-proven pattern)
__device__ __forceinline__ void poll_load16(bf16x8 (&d)[16], const short* p) {
  asm volatile(
    "global_load_dwordx4 %0, %16, off sc0 sc1\n\t"
    "global_load_dwordx4 %1, %16, off offset:64 sc0 sc1\n\t"
    "global_load_dwordx4 %2, %16, off offset:128 sc0 sc1\n\t"
    "global_load_dwordx4 %3, %16, off offset:192 sc0 sc1\n\t"
    "global_load_dwordx4 %4, %16, off offset:256 sc0 sc1\n\t"
    "global_load_dwordx4 %5, %16, off offset:320 sc0 sc1\n\t"
    "global_load_dwordx4 %6, %16, off offset:384 sc0 sc1\n\t"
    "global_load_dwordx4 %7, %16, off offset:448 sc0 sc1\n\t"
    "global_load_dwordx4 %8, %16, off offset:512 sc0 sc1\n\t"
    "global_load_dwordx4 %9, %16, off offset:576 sc0 sc1\n\t"
    "global_load_dwordx4 %10, %16, off offset:640 sc0 sc1\n\t"
    "global_load_dwordx4 %11, %16, off offset:704 sc0 sc1\n\t"
    "global_load_dwordx4 %12, %16, off offset:768 sc0 sc1\n\t"
    "global_load_dwordx4 %13, %16, off offset:832 sc0 sc1\n\t"
    "global_load_dwordx4 %14, %16, off offset:896 sc0 sc1\n\t"
    "global_load_dwordx4 %15, %16, off offset:960 sc0 sc1\n\t"
    "s_waitcnt vmcnt(0)"
    : "=&v"(d[0]), "=&v"(d[1]), "=&v"(d[2]), "=&v"(d[3]),
      "=&v"(d[4]), "=&v"(d[5]), "=&v"(d[6]), "=&v"(d[7]),
      "=&v"(d[8]), "=&v"(d[9]), "=&v"(d[10]), "=&v"(d[11]),
      "=&v"(d[12]), "=&v"(d[13]), "=&v"(d[14]), "=&v"(d[15])
    : "v"(p)
    : "memory");
}

__device__ __forceinline__ int valid16(const bf16x8 (&a)[16]) {
  uint32_t ok = 1;
#pragma unroll
  for (int i = 0; i < 16; ++i) {
    u32x4 q = __builtin_bit_cast(u32x4, a[i]);
    ok &= (q[0] != SENT) & (q[1] != SENT) & (q[2] != SENT) & (q[3] != SENT);
  }
  return (int)ok;
}

// sentinel-fill the H buffers
__global__ void fill_sent(uint32_t* __restrict__ p, size_t n16) {
  u32x4 s = {SENT, SENT, SENT, SENT};
  for (size_t i = blockIdx.x * blockDim.x + threadIdx.x; i < n16;
       i += (size_t)gridDim.x * blockDim.x)
    st16_wt(p + i * 4, s);
}

// Per-WAVE self-contained scan: wave owns 4 units x ALL 4 gates x 16 rows.
// B cols = 4*ul + g -> global col g*512 + unit. Gate exchange = in-register
// 4x4 lane transpose (no LDS, no barriers anywhere in the loop).
// x[t+1] polled at iteration END (overlaps h store transit).
template<int XSTEPS, bool XF32>
__device__ void scan_wave(
    int jbw, int rbase,
    const float* __restrict__ xf,       // [B][T][D] (layer 0 only)
    const short* __restrict__ Hprev,    // prev layer H [T+1][32][512]
    short*       __restrict__ Hown,     // own H [T+1][32][512]
    const float* __restrict__ W,        // [KX][2048]
    const float* __restrict__ R,        // [512][2048]
    const float* __restrict__ bias,     // [2048]
    const float* __restrict__ hinit,    // [512]
    const float* __restrict__ cinit)    // [512]
{
  const int lane = threadIdx.x & 63;
  const int arow = lane & 15;           // A row (batch row within group)
  const int kq   = lane >> 4;           // k-quarter
  const int g    = lane & 3;            // pre-transpose gate / post-transpose row offset
  const int ul   = (lane >> 2) & 3;     // unit-local (stable across transpose)
  const int unit = jbw + ul;            // this lane's unit
  const int gbase = lane & 60;          // first lane of my 4-lane gate group
  const int myrow = rbase + kq * 4 + g; // post-transpose output row

  // ---- one-time: weight B-fragments into registers (col = g*512 + unit) ----
  bf16x8 bw[XSTEPS], br[16];
  const int colg = g * UU + unit;
#pragma unroll
  for (int ks = 0; ks < XSTEPS; ++ks) {
    bf16x8 v;
#pragma unroll
    for (int jj = 0; jj < 8; ++jj)
      v[jj] = f2bf(W[(size_t)(ks * 32 + kq * 8 + jj) * 2048 + colg]);
    bw[ks] = v;
  }
#pragma unroll
  for (int ks = 0; ks < 16; ++ks) {
    bf16x8 v;
#pragma unroll
    for (int jj = 0; jj < 8; ++jj)
      v[jj] = f2bf(R[(size_t)(ks * 32 + kq * 8 + jj) * 2048 + colg]);
    br[ks] = v;
  }

  float biasv[4];
#pragma unroll
  for (int G = 0; G < 4; ++G) biasv[G] = bias[G * UU + unit];
  float cr = cinit[unit];

  // ---- init tile 0: even-ul lanes store one packed dword ----
  if ((ul & 1) == 0) {
    uint32_t pk = pack2(hinit[unit], hinit[unit + 1]);
    st4_wt(Hown + (size_t)myrow * UU + unit, pk);
  }

  int budget = 1 << 18;                 // termination valve (never hang)

  // ---- x cache in registers; prologue fill for t=0 ----
  bf16x8 xc[XF32 ? XSTEPS : 16];
  if constexpr (XF32) {
    const float* p = xf + ((size_t)(rbase + arow) * SEQT + 0) * DIM + kq * 8;
#pragma unroll
    for (int ks = 0; ks < XSTEPS; ++ks) {
      float4 x0 = *(const float4*)(p + ks * 32);
      float4 x1 = *(const float4*)(p + ks * 32 + 4);
      bf16x8 a;
      a[0] = f2bf(x0.x); a[1] = f2bf(x0.y); a[2] = f2bf(x0.z); a[3] = f2bf(x0.w);
      a[4] = f2bf(x1.x); a[5] = f2bf(x1.y); a[6] = f2bf(x1.z); a[7] = f2bf(x1.w);
      xc[ks] = a;
    }
  } else {
    const short* xp = Hprev + ((size_t)1 * BATCH + rbase + arow) * UU + kq * 8;
    while (true) {
      poll_load16(xc, xp);
      if (__all(valid16(xc))) break;
      if (--budget < 0) break;
    }
  }

#pragma unroll 1
  for (int t = 0; t < SEQT; ++t) {
    // ---- h poll (critical path): detect+load = one RTT per iteration ----
    bf16x8 ha[16];
    {
      const short* hp = Hown + ((size_t)t * BATCH + rbase + arow) * UU + kq * 8;
      while (true) {
        poll_load16(ha, hp);
        if (__all(valid16(ha))) break;
        if (--budget < 0) break;
      }
    }

    // ---- MFMAs: 4 independent accumulator chains ----
    f32x4 c0 = {0.f,0.f,0.f,0.f}, c1 = {0.f,0.f,0.f,0.f};
    f32x4 c2 = {0.f,0.f,0.f,0.f}, c3 = {0.f,0.f,0.f,0.f};
#pragma unroll
    for (int ks = 0; ks < XSTEPS; ++ks) {
      f32x4& ac = (ks & 2) ? ((ks & 1) ? c3 : c2) : ((ks & 1) ? c1 : c0);
      ac = __builtin_amdgcn_mfma_f32_16x16x32_bf16(xc[ks], bw[ks], ac, 0, 0, 0);
    }
#pragma unroll
    for (int ks = 0; ks < 16; ++ks) {
      f32x4& ac = (ks & 2) ? ((ks & 1) ? c3 : c2) : ((ks & 1) ? c1 : c0);
      ac = __builtin_amdgcn_mfma_f32_16x16x32_bf16(ha[ks], br[ks], ac, 0, 0, 0);
    }
    f32x4 acc = (c0 + c1) + (c2 + c3);
    // acc[r] = z[row kq*4+r][col 4*ul+g]

    // ---- in-register 4x4 (gate x row) lane transpose ----
    // zz[G] = z_G for (row kq*4+g, unit ul)
    float zz[4];
#pragma unroll
    for (int G = 0; G < 4; ++G) {
      float v0 = __shfl(acc[0], gbase + G);
      float v1 = __shfl(acc[1], gbase + G);
      float v2 = __shfl(acc[2], gbase + G);
      float v3 = __shfl(acc[3], gbase + G);
      float v = (g == 1) ? v1 : v0;
      v = (g == 2) ? v2 : v;
      v = (g == 3) ? v3 : v;
      zz[G] = v;
    }

    // ---- gates + state (fp32), every lane owns one (row, unit) ----
    float zi = zz[0] + biasv[0];
    float zf = zz[1] + biasv[1];
    float zg = zz[2] + biasv[2];
    float zo = zz[3] + biasv[3];
    cr = sigm(zf) * cr + sigm(zi) * tanh_fast(zg);
    float hv = sigm(zo) * tanh_fast(cr);

    // ---- pair units (ul, ul+1) -> one 4B fire-and-forget store ----
    float hq = __shfl_xor(hv, 4);
    if ((ul & 1) == 0) {
      st4_wt(Hown + ((size_t)(t + 1) * BATCH + myrow) * UU + unit, pack2(hv, hq));
    }

    // ---- x prefetch for t+1 (spin overlaps our h-store transit) ----
    if (t + 1 < SEQT) {
      if constexpr (XF32) {
        const float* p = xf + ((size_t)(rbase + arow) * SEQT + (t + 1)) * DIM + kq * 8;
#pragma unroll
        for (int ks = 0; ks < XSTEPS; ++ks) {
          float4 x0 = *(const float4*)(p + ks * 32);
          float4 x1 = *(const float4*)(p + ks * 32 + 4);
          bf16x8 a;
          a[0] = f2bf(x0.x); a[1] = f2bf(x0.y); a[2] = f2bf(x0.z); a[3] = f2bf(x0.w);
          a[4] = f2bf(x1.x); a[5] = f2bf(x1.y); a[6] = f2bf(x1.z); a[7] = f2bf(x1.w);
          xc[ks] = a;
        }
      } else {
        const short* xp = Hprev + ((size_t)(t + 2) * BATCH + rbase + arow) * UU + kq * 8;
        while (true) {
          poll_load16(xc, xp);
          if (__all(valid16(xc))) break;
          if (--budget < 0) break;
        }
      }
    }
  }
}

__global__ __launch_bounds__(256, 1) void lstm_scan(
    const float* __restrict__ inputs,
    const float* __restrict__ W0, const float* __restrict__ R0, const float* __restrict__ b0,
    const float* __restrict__ h0i, const float* __restrict__ c0i,
    const float* __restrict__ W1, const float* __restrict__ R1, const float* __restrict__ b1,
    const float* __restrict__ h1i, const float* __restrict__ c1i,
    const float* __restrict__ W2, const float* __restrict__ R2, const float* __restrict__ b2,
    const float* __restrict__ h2i, const float* __restrict__ c2i,
    short* __restrict__ H0, short* __restrict__ H1, short* __restrict__ H2)
{
  const int layer = blockIdx.x >> 6;    // 0..2
  const int sub   = blockIdx.x & 63;
  const int jblk  = sub & 31;
  const int rbase = (sub >> 5) * 16;
  const int wave  = threadIdx.x >> 6;
  const int jbw   = jblk * 16 + wave * 4;   // this wave's unit base

  if (layer == 0)
    scan_wave<8,  true >(jbw, rbase, inputs, nullptr, H0, W0, R0, b0, h0i, c0i);
  else if (layer == 1)
    scan_wave<16, false>(jbw, rbase, nullptr, H0, H1, W1, R1, b1, h1i, c1i);
  else
    scan_wave<16, false>(jbw, rbase, nullptr, H1, H2, W2, R2, b2, h2i, c2i);
}

// Y[b][t][:] = H2[t+1][b][:] @ Wd + bd.  Tile: 128 rows x 64 cols per WG.
__global__ __launch_bounds__(256, 2) void dense_out(
    const short* __restrict__ H2,      // [T+1][32][512]
    const float* __restrict__ Wd,      // [512][256]
    const float* __restrict__ bd,      // [256]
    float* __restrict__ out)           // [32][512][256]
{
  const int mblock = blockIdx.x;       // 0..127
  const int nblock = blockIdx.y;       // 0..3
  const int tid  = threadIdx.x;
  const int wave = tid >> 6;
  const int lane = tid & 63;
  const int col  = lane & 15;
  const int kq   = lane >> 4;

  __shared__ short wlds[64][264];

  f32x4 acc[2][4];
#pragma unroll
  for (int mi = 0; mi < 2; ++mi)
#pragma unroll
    for (int ni = 0; ni < 4; ++ni)
      acc[mi][ni] = f32x4{0.f, 0.f, 0.f, 0.f};

  const short* Abase = H2 + (size_t)32 * UU;   // skip init tile

  for (int half = 0; half < 2; ++half) {
    __syncthreads();
    for (int idx = tid; idx < 256 * 64; idx += 256) {
      int k = idx >> 6;
      int c = idx & 63;
      wlds[c][k] = f2bf(Wd[(size_t)(half * 256 + k) * 256 + nblock * 64 + c]);
    }
    __syncthreads();
#pragma unroll
    for (int ks = 0; ks < 8; ++ks) {
      const int d0g = half * 256 + ks * 32 + kq * 8;
      const int d0l = ks * 32 + kq * 8;
      const size_t r0 = (size_t)(mblock * 128 + wave * 32 + col) * UU;
      const size_t r1 = (size_t)(mblock * 128 + wave * 32 + 16 + col) * UU;
      bf16x8 a0 = *(const bf16x8*)(Abase + r0 + d0g);
      bf16x8 a1 = *(const bf16x8*)(Abase + r1 + d0g);
#pragma unroll
      for (int ni = 0; ni < 4; ++ni) {
        bf16x8 bv = *(const bf16x8*)(&wlds[ni * 16 + col][d0l]);
        acc[0][ni] = __builtin_amdgcn_mfma_f32_16x16x32_bf16(a0, bv, acc[0][ni], 0, 0, 0);
        acc[1][ni] = __builtin_amdgcn_mfma_f32_16x16x32_bf16(a1, bv, acc[1][ni], 0, 0, 0);
      }
    }
  }

#pragma unroll
  for (int ni = 0; ni < 4; ++ni) {
    float bdv = bd[nblock * 64 + ni * 16 + col];
#pragma unroll
    for (int mi = 0; mi < 2; ++mi) {
#pragma unroll
      for (int r = 0; r < 4; ++r) {
        int grow = mblock * 128 + wave * 32 + mi * 16 + kq * 4 + r;
        int t = grow >> 5, b = grow & 31;
        out[((size_t)b * SEQT + t) * DIM + nblock * 64 + ni * 16 + col] = acc[mi][ni][r] + bdv;
      }
    }
  }
}

extern "C" void kernel_launch(void* const* d_in, const int* in_sizes, int n_in,
                              void* d_out, int out_size, void* d_ws, size_t ws_size,
                              hipStream_t stream) {
  const float* inputs = (const float*)d_in[0];
  const float* W0 = (const float*)d_in[1];
  const float* R0 = (const float*)d_in[2];
  const float* b0 = (const float*)d_in[3];
  const float* h0 = (const float*)d_in[4];
  const float* c0 = (const float*)d_in[5];
  const float* W1 = (const float*)d_in[6];
  const float* R1 = (const float*)d_in[7];
  const float* b1 = (const float*)d_in[8];
  const float* h1 = (const float*)d_in[9];
  const float* c1 = (const float*)d_in[10];
  const float* W2 = (const float*)d_in[11];
  const float* R2 = (const float*)d_in[12];
  const float* b2 = (const float*)d_in[13];
  const float* h2 = (const float*)d_in[14];
  const float* c2 = (const float*)d_in[15];
  const float* Wd = (const float*)d_in[16];
  const float* bd = (const float*)d_in[17];

  char* base = (char*)d_ws;
  const size_t HX = (size_t)(SEQT + 1) * BATCH * UU * sizeof(short); // ~16.8 MB
  short* H0 = (short*)(base);
  short* H1 = (short*)(base + HX);
  short* H2 = (short*)(base + 2 * HX);

  // re-arm sentinels every launch (replay-safe)
  const size_t n16 = 3 * HX / 16;
  hipLaunchKernelGGL(fill_sent, dim3(2048), dim3(256), 0, stream,
                     (uint32_t*)base, n16);

  hipLaunchKernelGGL(lstm_scan, dim3(192), dim3(256), 0, stream,
                     inputs, W0, R0, b0, h0, c0, W1, R1, b1, h1, c1,
                     W2, R2, b2, h2, c2, H0, H1, H2);

  hipLaunchKernelGGL(dense_out, dim3(128, 4), dim3(256), 0, stream,
                     H2, Wd, bd, (float*)d_out);
}

// Round 13
// 2173.418 us; speedup vs baseline: 1.6034x; 1.6034x over previous
//
#include <hip/hip_runtime.h>
#include <hip/hip_bf16.h>
#include <stdint.h>

#define BATCH 32
#define SEQT  512
#define DIM   256
#define UU    512
#define SENT  0x7FC07FC0u   // bf16 NaN pair: finite h/x data can never equal this

typedef __attribute__((ext_vector_type(8))) short bf16x8;
typedef __attribute__((ext_vector_type(4))) float f32x4;
typedef __attribute__((ext_vector_type(4))) unsigned int u32x4;

__device__ __forceinline__ short f2bf(float f) {
  uint32_t u = __builtin_bit_cast(uint32_t, f);
  u += 0x7FFFu + ((u >> 16) & 1u);   // RNE; finite in -> finite out (never NaN)
  return (short)(u >> 16);
}
__device__ __forceinline__ float sigm(float x) { return 1.0f / (1.0f + __expf(-x)); }
__device__ __forceinline__ float tanh_fast(float x) {
  float ax = fabsf(x);
  float t = __expf(-2.0f * ax);
  float r = (1.0f - t) / (1.0f + t);
  return copysignf(r, x);
}

// 16B write-through store (visible at LLC); fire-and-forget
__device__ __forceinline__ void st16_wt(void* p, u32x4 v) {
  asm volatile("global_store_dwordx4 %0, %1, off sc0 sc1" :: "v"(p), "v"(v) : "memory");
}

// 4x 16B LLC-coherent loads + waitcnt inside one asm block (safe pattern, r9 syntax)
__device__ __forceinline__ void poll_load4(bf16x8 (&d)[4], const short* p) {
  asm volatile(
    "global_load_dwordx4 %0, %4, off sc0 sc1\n\t"
    "global_load_dwordx4 %1, %4, off offset:64 sc0 sc1\n\t"
    "global_load_dwordx4 %2, %4, off offset:128 sc0 sc1\n\t"
    "global_load_dwordx4 %3, %4, off offset:192 sc0 sc1\n\t"
    "s_waitcnt vmcnt(0)"
    : "=&v"(d[0]), "=&v"(d[1]), "=&v"(d[2]), "=&v"(d[3])
    : "v"(p)
    : "memory");
}

__device__ __forceinline__ int valid4(const bf16x8 (&a)[4]) {
  uint32_t ok = 1;
#pragma unroll
  for (int i = 0; i < 4; ++i) {
    u32x4 q = __builtin_bit_cast(u32x4, a[i]);
    ok &= (q[0] != SENT) & (q[1] != SENT) & (q[2] != SENT) & (q[3] != SENT);
  }
  return (int)ok;
}

// sentinel-fill the H buffers
__global__ void fill_sent(uint32_t* __restrict__ p, size_t n16) {
  u32x4 s = {SENT, SENT, SENT, SENT};
  for (size_t i = blockIdx.x * blockDim.x + threadIdx.x; i < n16;
       i += (size_t)gridDim.x * blockDim.x)
    st16_wt(p + i * 4, s);
}

// K-split scan: 64 WGs/layer = 32 unit-blocks x 2 row-groups. WG owns 16 units
// (all 4 gates) x 16 rows. Wave w owns k in [128w,128w+128): polls only its 4KB
// quarter of the h (and x) tile; partial z reduced through LDS; every lane then
// holds all 4 gates of its (row,unit) in registers -> no cross-lane exchange.
template<bool XF32>
__device__ void scan_body(
    int jblk, int rbase,
    const float* __restrict__ xf,       // [B][T][D] (layer 0 only)
    const short* __restrict__ Hprev,    // prev layer H [T+1][32][512]
    short*       __restrict__ Hown,     // own H [T+1][32][512]
    const float* __restrict__ W,        // [KX][2048]
    const float* __restrict__ R,        // [512][2048]
    const float* __restrict__ bias,     // [2048]
    const float* __restrict__ hinit,    // [512]
    const float* __restrict__ cinit)    // [512]
{
  const int tid  = threadIdx.x;
  const int w    = tid >> 6;            // wave = k-quarter owner
  const int lane = tid & 63;
  const int arow = lane & 15;           // A row index AND C unit index
  const int kq   = lane >> 4;
  const int jbase = jblk * 16;
  const int unit  = jbase + arow;       // this lane's unit (C col)

  constexpr int XK = XF32 ? 2 : 4;      // x k-chunks per wave

  // ---- one-time: weight B-fragments into registers (col = gate*512 + unit) ----
  bf16x8 bw[4][XK], br[4][4];
#pragma unroll
  for (int cg = 0; cg < 4; ++cg) {
    const int col = cg * UU + unit;
#pragma unroll
    for (int ks = 0; ks < XK; ++ks) {
      bf16x8 v;
#pragma unroll
      for (int jj = 0; jj < 8; ++jj)
        v[jj] = f2bf(W[(size_t)((XF32 ? 64 : 128) * w + ks * 32 + kq * 8 + jj) * 2048 + col]);
      bw[cg][ks] = v;
    }
#pragma unroll
    for (int ks = 0; ks < 4; ++ks) {
      bf16x8 v;
#pragma unroll
      for (int jj = 0; jj < 8; ++jj)
        v[jj] = f2bf(R[(size_t)(128 * w + ks * 32 + kq * 8 + jj) * 2048 + col]);
      br[cg][ks] = v;
    }
  }

  float biasv[4];
#pragma unroll
  for (int cg = 0; cg < 4; ++cg) biasv[cg] = bias[cg * UU + unit];
  float cr[4];
  {
    float ci = cinit[unit];
#pragma unroll
    for (int r = 0; r < 4; ++r) cr[r] = ci;
  }

  __shared__ f32x4 zp[4][16][16];       // [w][row][unit] -> 4-gate partial vec
  __shared__ short hsm[16][18];         // h regather (row x unit), padded

  // ---- init tile 0 ----
  {
    short hb = f2bf(hinit[unit]);
#pragma unroll
    for (int r = 0; r < 4; ++r) hsm[kq * 4 + r][arow] = hb;   // same value, benign race
  }
  __syncthreads();
  if (tid < 32) {
    int row = tid >> 1, q = tid & 1;
    uint32_t d0 = (uint16_t)hsm[row][q*8+0] | ((uint32_t)(uint16_t)hsm[row][q*8+1] << 16);
    uint32_t d1 = (uint16_t)hsm[row][q*8+2] | ((uint32_t)(uint16_t)hsm[row][q*8+3] << 16);
    uint32_t d2 = (uint16_t)hsm[row][q*8+4] | ((uint32_t)(uint16_t)hsm[row][q*8+5] << 16);
    uint32_t d3 = (uint16_t)hsm[row][q*8+6] | ((uint32_t)(uint16_t)hsm[row][q*8+7] << 16);
    u32x4 v = {d0, d1, d2, d3};
    st16_wt(Hown + (size_t)(rbase + row) * UU + jbase + q * 8, v);
  }

  int budget = 1 << 18;                 // termination valve (never hang)

#pragma unroll 1
  for (int t = 0; t < SEQT; ++t) {
    // ---- x fetch (before h-poll: overlaps h store transit) ----
    bf16x8 xa[XK];
    if constexpr (XF32) {
      const float* p = xf + ((size_t)(rbase + arow) * SEQT + t) * DIM + 64 * w + kq * 8;
#pragma unroll
      for (int ks = 0; ks < XK; ++ks) {
        float4 x0 = *(const float4*)(p + ks * 32);
        float4 x1 = *(const float4*)(p + ks * 32 + 4);
        bf16x8 a;
        a[0] = f2bf(x0.x); a[1] = f2bf(x0.y); a[2] = f2bf(x0.z); a[3] = f2bf(x0.w);
        a[4] = f2bf(x1.x); a[5] = f2bf(x1.y); a[6] = f2bf(x1.z); a[7] = f2bf(x1.w);
        xa[ks] = a;
      }
    } else {
      const short* xp = Hprev + ((size_t)(t + 1) * BATCH + rbase + arow) * UU + 128 * w + kq * 8;
      bf16x8 xq[4];
      while (true) {
        poll_load4(xq, xp);
        if (__all(valid4(xq))) break;
        if (--budget < 0) break;
      }
#pragma unroll
      for (int ks = 0; ks < 4; ++ks) xa[ks] = xq[ks];
    }

    // ---- h poll: only this wave's 4KB k-quarter ----
    bf16x8 ha[4];
    {
      const short* hp = Hown + ((size_t)t * BATCH + rbase + arow) * UU + 128 * w + kq * 8;
      while (true) {
        poll_load4(ha, hp);
        if (__all(valid4(ha))) break;
        if (--budget < 0) break;
      }
    }

    // ---- partial MFMAs: 4 chains (one per gate) ----
    f32x4 acc[4];
#pragma unroll
    for (int cg = 0; cg < 4; ++cg) acc[cg] = f32x4{0.f, 0.f, 0.f, 0.f};
#pragma unroll
    for (int cg = 0; cg < 4; ++cg) {
#pragma unroll
      for (int ks = 0; ks < XK; ++ks)
        acc[cg] = __builtin_amdgcn_mfma_f32_16x16x32_bf16(xa[ks], bw[cg][ks], acc[cg], 0, 0, 0);
#pragma unroll
      for (int ks = 0; ks < 4; ++ks)
        acc[cg] = __builtin_amdgcn_mfma_f32_16x16x32_bf16(ha[ks], br[cg][ks], acc[cg], 0, 0, 0);
    }

    // ---- write gate-vec partials (b128), reduce in fixed order ----
#pragma unroll
    for (int r = 0; r < 4; ++r) {
      f32x4 zv = {acc[0][r], acc[1][r], acc[2][r], acc[3][r]};
      zp[w][kq * 4 + r][arow] = zv;
    }
    __syncthreads();   // B1: all partials visible

#pragma unroll
    for (int r = 0; r < 4; ++r) {
      const int row = kq * 4 + r;
      f32x4 s = zp[0][row][arow];
      s += zp[1][row][arow];
      s += zp[2][row][arow];
      s += zp[3][row][arow];     // fixed order -> bit-identical across waves
      float zi = s[0] + biasv[0];
      float zf = s[1] + biasv[1];
      float zg = s[2] + biasv[2];
      float zo = s[3] + biasv[3];
      cr[r] = sigm(zf) * cr[r] + sigm(zi) * tanh_fast(zg);
      hsm[row][arow] = f2bf(sigm(zo) * tanh_fast(cr[r]));   // same value from all waves
    }
    __syncthreads();   // B2: hsm complete; zp safe for reuse

    // ---- 32 x 16B fire-and-forget stores; NO drain, NO publish ----
    if (tid < 32) {
      int row = tid >> 1, q = tid & 1;
      uint32_t d0 = (uint16_t)hsm[row][q*8+0] | ((uint32_t)(uint16_t)hsm[row][q*8+1] << 16);
      uint32_t d1 = (uint16_t)hsm[row][q*8+2] | ((uint32_t)(uint16_t)hsm[row][q*8+3] << 16);
      uint32_t d2 = (uint16_t)hsm[row][q*8+4] | ((uint32_t)(uint16_t)hsm[row][q*8+5] << 16);
      uint32_t d3 = (uint16_t)hsm[row][q*8+6] | ((uint32_t)(uint16_t)hsm[row][q*8+7] << 16);
      u32x4 v = {d0, d1, d2, d3};
      st16_wt(Hown + ((size_t)(t + 1) * BATCH + rbase + row) * UU + jbase + q * 8, v);
    }
  }
}

__global__ __launch_bounds__(256, 1) void lstm_scan(
    const float* __restrict__ inputs,
    const float* __restrict__ W0, const float* __restrict__ R0, const float* __restrict__ b0,
    const float* __restrict__ h0i, const float* __restrict__ c0i,
    const float* __restrict__ W1, const float* __restrict__ R1, const float* __restrict__ b1,
    const float* __restrict__ h1i, const float* __restrict__ c1i,
    const float* __restrict__ W2, const float* __restrict__ R2, const float* __restrict__ b2,
    const float* __restrict__ h2i, const float* __restrict__ c2i,
    short* __restrict__ H0, short* __restrict__ H1, short* __restrict__ H2)
{
  const int layer = blockIdx.x >> 6;    // 0..2
  const int sub   = blockIdx.x & 63;
  const int jblk  = sub & 31;
  const int rbase = (sub >> 5) * 16;

  if (layer == 0)
    scan_body<true >(jblk, rbase, inputs, nullptr, H0, W0, R0, b0, h0i, c0i);
  else if (layer == 1)
    scan_body<false>(jblk, rbase, nullptr, H0, H1, W1, R1, b1, h1i, c1i);
  else
    scan_body<false>(jblk, rbase, nullptr, H1, H2, W2, R2, b2, h2i, c2i);
}

// Y[b][t][:] = H2[t+1][b][:] @ Wd + bd.  Tile: 128 rows x 64 cols per WG.
__global__ __launch_bounds__(256, 2) void dense_out(
    const short* __restrict__ H2,      // [T+1][32][512]
    const float* __restrict__ Wd,      // [512][256]
    const float* __restrict__ bd,      // [256]
    float* __restrict__ out)           // [32][512][256]
{
  const int mblock = blockIdx.x;       // 0..127
  const int nblock = blockIdx.y;       // 0..3
  const int tid  = threadIdx.x;
  const int wave = tid >> 6;
  const int lane = tid & 63;
  const int col  = lane & 15;
  const int kq   = lane >> 4;

  __shared__ short wlds[64][264];

  f32x4 acc[2][4];
#pragma unroll
  for (int mi = 0; mi < 2; ++mi)
#pragma unroll
    for (int ni = 0; ni < 4; ++ni)
      acc[mi][ni] = f32x4{0.f, 0.f, 0.f, 0.f};

  const short* Abase = H2 + (size_t)32 * UU;   // skip init tile

  for (int half = 0; half < 2; ++half) {
    __syncthreads();
    for (int idx = tid; idx < 256 * 64; idx += 256) {
      int k = idx >> 6;
      int c = idx & 63;
      wlds[c][k] = f2bf(Wd[(size_t)(half * 256 + k) * 256 + nblock * 64 + c]);
    }
    __syncthreads();
#pragma unroll
    for (int ks = 0; ks < 8; ++ks) {
      const int d0g = half * 256 + ks * 32 + kq * 8;
      const int d0l = ks * 32 + kq * 8;
      const size_t r0 = (size_t)(mblock * 128 + wave * 32 + col) * UU;
      const size_t r1 = (size_t)(mblock * 128 + wave * 32 + 16 + col) * UU;
      bf16x8 a0 = *(const bf16x8*)(Abase + r0 + d0g);
      bf16x8 a1 = *(const bf16x8*)(Abase + r1 + d0g);
#pragma unroll
      for (int ni = 0; ni < 4; ++ni) {
        bf16x8 bv = *(const bf16x8*)(&wlds[ni * 16 + col][d0l]);
        acc[0][ni] = __builtin_amdgcn_mfma_f32_16x16x32_bf16(a0, bv, acc[0][ni], 0, 0, 0);
        acc[1][ni] = __builtin_amdgcn_mfma_f32_16x16x32_bf16(a1, bv, acc[1][ni], 0, 0, 0);
      }
    }
  }

#pragma unroll
  for (int ni = 0; ni < 4; ++ni) {
    float bdv = bd[nblock * 64 + ni * 16 + col];
#pragma unroll
    for (int mi = 0; mi < 2; ++mi) {
#pragma unroll
      for (int r = 0; r < 4; ++r) {
        int grow = mblock * 128 + wave * 32 + mi * 16 + kq * 4 + r;
        int t = grow >> 5, b = grow & 31;
        out[((size_t)b * SEQT + t) * DIM + nblock * 64 + ni * 16 + col] = acc[mi][ni][r] + bdv;
      }
    }
  }
}

extern "C" void kernel_launch(void* const* d_in, const int* in_sizes, int n_in,
                              void* d_out, int out_size, void* d_ws, size_t ws_size,
                              hipStream_t stream) {
  const float* inputs = (const float*)d_in[0];
  const float* W0 = (const float*)d_in[1];
  const float* R0 = (const float*)d_in[2];
  const float* b0 = (const float*)d_in[3];
  const float* h0 = (const float*)d_in[4];
  const float* c0 = (const float*)d_in[5];
  const float* W1 = (const float*)d_in[6];
  const float* R1 = (const float*)d_in[7];
  const float* b1 = (const float*)d_in[8];
  const float* h1 = (const float*)d_in[9];
  const float* c1 = (const float*)d_in[10];
  const float* W2 = (const float*)d_in[11];
  const float* R2 = (const float*)d_in[12];
  const float* b2 = (const float*)d_in[13];
  const float* h2 = (const float*)d_in[14];
  const float* c2 = (const float*)d_in[15];
  const float* Wd = (const float*)d_in[16];
  const float* bd = (const float*)d_in[17];

  char* base = (char*)d_ws;
  const size_t HX = (size_t)(SEQT + 1) * BATCH * UU * sizeof(short); // ~16.8 MB
  short* H0 = (short*)(base);
  short* H1 = (short*)(base + HX);
  short* H2 = (short*)(base + 2 * HX);

  // re-arm sentinels every launch (replay-safe)
  const size_t n16 = 3 * HX / 16;
  hipLaunchKernelGGL(fill_sent, dim3(2048), dim3(256), 0, stream,
                     (uint32_t*)base, n16);

  hipLaunchKernelGGL(lstm_scan, dim3(192), dim3(256), 0, stream,
                     inputs, W0, R0, b0, h0, c0, W1, R1, b1, h1, c1,
                     W2, R2, b2, h2, c2, H0, H1, H2);

  hipLaunchKernelGGL(dense_out, dim3(128, 4), dim3(256), 0, stream,
                     H2, Wd, bd, (float*)d_out);
}

// Round 15
// 2154.189 us; speedup vs baseline: 1.6177x; 1.0089x over previous
//
#include <hip/hip_runtime.h>
#include <hip/hip_bf16.h>
#include <stdint.h>

#define BATCH 32
#define SEQT  512
#define DIM   256
#define UU    512
#define SENT  0x7FC07FC0u   // bf16 NaN pair: finite h/x data can never equal this
#define POISN 0xAAAAAAAAu   // harness poison pattern: also treated as not-ready

typedef __attribute__((ext_vector_type(8))) short bf16x8;
typedef __attribute__((ext_vector_type(4))) float f32x4;
typedef __attribute__((ext_vector_type(4))) unsigned int u32x4;

__device__ __forceinline__ short f2bf(float f) {
  uint32_t u = __builtin_bit_cast(uint32_t, f);
  u += 0x7FFFu + ((u >> 16) & 1u);   // RNE; finite in -> finite out (never NaN)
  return (short)(u >> 16);
}
__device__ __forceinline__ float sigm(float x) { return 1.0f / (1.0f + __expf(-x)); }
__device__ __forceinline__ float tanh_fast(float x) {
  float ax = fabsf(x);
  float t = __expf(-2.0f * ax);
  float r = (1.0f - t) / (1.0f + t);
  return copysignf(r, x);
}

// 16B write-through store (visible at LLC); fire-and-forget
__device__ __forceinline__ void st16_wt(void* p, u32x4 v) {
  asm volatile("global_store_dwordx4 %0, %1, off sc0 sc1" :: "v"(p), "v"(v) : "memory");
}

// 4x 16B LLC-coherent loads + waitcnt inside one asm block (safe pattern)
__device__ __forceinline__ void poll_load4(bf16x8 (&d)[4], const short* p) {
  asm volatile(
    "global_load_dwordx4 %0, %4, off sc0 sc1\n\t"
    "global_load_dwordx4 %1, %4, off offset:64 sc0 sc1\n\t"
    "global_load_dwordx4 %2, %4, off offset:128 sc0 sc1\n\t"
    "global_load_dwordx4 %3, %4, off offset:192 sc0 sc1\n\t"
    "s_waitcnt vmcnt(0)"
    : "=&v"(d[0]), "=&v"(d[1]), "=&v"(d[2]), "=&v"(d[3])
    : "v"(p)
    : "memory");
}

__device__ __forceinline__ int valid4(const bf16x8 (&a)[4]) {
  uint32_t ok = 1;
#pragma unroll
  for (int i = 0; i < 4; ++i) {
    u32x4 q = __builtin_bit_cast(u32x4, a[i]);
#pragma unroll
    for (int j = 0; j < 4; ++j)
      ok &= (q[j] != SENT) & (q[j] != POISN);
  }
  return (int)ok;
}

// sentinel-fill the H buffers
__global__ void fill_sent(uint32_t* __restrict__ p, size_t n16) {
  u32x4 s = {SENT, SENT, SENT, SENT};
  for (size_t i = blockIdx.x * blockDim.x + threadIdx.x; i < n16;
       i += (size_t)gridDim.x * blockDim.x)
    st16_wt(p + i * 4, s);
}

// K-split scan (r13 structure): 64 WGs/layer = 32 unit-blocks x 2 row-groups.
// WG owns 16 units (all 4 gates) x 16 rows. Wave w owns k in [128w,128w+128).
// r15: wave-0-only epilogue (reduce+gates+store), zp parity double-buffer,
// B2 barrier eliminated; hsm is wave-0-private (same-wave LDS, no barrier).
template<bool XF32>
__device__ void scan_body(
    int jblk, int rbase,
    const float* __restrict__ xf,       // [B][T][D] (layer 0 only)
    const short* __restrict__ Hprev,    // prev layer H [T+1][32][512]
    short*       __restrict__ Hown,     // own H [T+1][32][512]
    const float* __restrict__ W,        // [KX][2048]
    const float* __restrict__ R,        // [512][2048]
    const float* __restrict__ bias,     // [2048]
    const float* __restrict__ hinit,    // [512]
    const float* __restrict__ cinit)    // [512]
{
  const int tid  = threadIdx.x;
  const int w    = tid >> 6;            // wave = k-quarter owner
  const int lane = tid & 63;
  const int arow = lane & 15;           // A row index AND C unit index
  const int kq   = lane >> 4;
  const int jbase = jblk * 16;
  const int unit  = jbase + arow;       // this lane's unit (C col)

  constexpr int XK = XF32 ? 2 : 4;      // x k-chunks per wave

  // ---- one-time: weight B-fragments into registers (col = gate*512 + unit) ----
  bf16x8 bw[4][XK], br[4][4];
#pragma unroll
  for (int cg = 0; cg < 4; ++cg) {
    const int col = cg * UU + unit;
#pragma unroll
    for (int ks = 0; ks < XK; ++ks) {
      bf16x8 v;
#pragma unroll
      for (int jj = 0; jj < 8; ++jj)
        v[jj] = f2bf(W[(size_t)((XF32 ? 64 : 128) * w + ks * 32 + kq * 8 + jj) * 2048 + col]);
      bw[cg][ks] = v;
    }
#pragma unroll
    for (int ks = 0; ks < 4; ++ks) {
      bf16x8 v;
#pragma unroll
      for (int jj = 0; jj < 8; ++jj)
        v[jj] = f2bf(R[(size_t)(128 * w + ks * 32 + kq * 8 + jj) * 2048 + col]);
      br[cg][ks] = v;
    }
  }

  float biasv[4];
#pragma unroll
  for (int cg = 0; cg < 4; ++cg) biasv[cg] = bias[cg * UU + unit];
  float cr[4];
  {
    float ci = cinit[unit];
#pragma unroll
    for (int r = 0; r < 4; ++r) cr[r] = ci;
  }

  __shared__ f32x4 zp[2][4][16][16];    // parity x [w][row][unit], 32KB
  __shared__ short hsm[16][18];         // wave-0-private h regather (padded)

  // ---- init tile 0 (wave 0 only; same-wave LDS needs no barrier) ----
  if (w == 0) {
    short hb = f2bf(hinit[unit]);
#pragma unroll
    for (int r = 0; r < 4; ++r) hsm[kq * 4 + r][arow] = hb;
    if (tid < 32) {
      int row = tid >> 1, q = tid & 1;
      uint32_t d0 = (uint16_t)hsm[row][q*8+0] | ((uint32_t)(uint16_t)hsm[row][q*8+1] << 16);
      uint32_t d1 = (uint16_t)hsm[row][q*8+2] | ((uint32_t)(uint16_t)hsm[row][q*8+3] << 16);
      uint32_t d2 = (uint16_t)hsm[row][q*8+4] | ((uint32_t)(uint16_t)hsm[row][q*8+5] << 16);
      uint32_t d3 = (uint16_t)hsm[row][q*8+6] | ((uint32_t)(uint16_t)hsm[row][q*8+7] << 16);
      u32x4 v = {d0, d1, d2, d3};
      st16_wt(Hown + (size_t)(rbase + row) * UU + jbase + q * 8, v);
    }
  }

  int budget = 1 << 18;                 // termination valve (never hang)

#pragma unroll 1
  for (int t = 0; t < SEQT; ++t) {
    const int par = t & 1;

    // ---- x fetch (r13 order: before h-poll; overlaps h store transit) ----
    bf16x8 xa[XK];
    if constexpr (XF32) {
      const float* p = xf + ((size_t)(rbase + arow) * SEQT + t) * DIM + 64 * w + kq * 8;
#pragma unroll
      for (int ks = 0; ks < XK; ++ks) {
        float4 x0 = *(const float4*)(p + ks * 32);
        float4 x1 = *(const float4*)(p + ks * 32 + 4);
        bf16x8 a;
        a[0] = f2bf(x0.x); a[1] = f2bf(x0.y); a[2] = f2bf(x0.z); a[3] = f2bf(x0.w);
        a[4] = f2bf(x1.x); a[5] = f2bf(x1.y); a[6] = f2bf(x1.z); a[7] = f2bf(x1.w);
        xa[ks] = a;
      }
    } else {
      const short* xp = Hprev + ((size_t)(t + 1) * BATCH + rbase + arow) * UU + 128 * w + kq * 8;
      bf16x8 xq[4];
      while (true) {
        poll_load4(xq, xp);
        if (__all(valid4(xq))) break;
        if (--budget < 0) break;
      }
#pragma unroll
      for (int ks = 0; ks < 4; ++ks) xa[ks] = xq[ks];
    }

    // ---- h poll: only this wave's 4KB k-quarter ----
    bf16x8 ha[4];
    {
      const short* hp = Hown + ((size_t)t * BATCH + rbase + arow) * UU + 128 * w + kq * 8;
      while (true) {
        poll_load4(ha, hp);
        if (__all(valid4(ha))) break;
        if (--budget < 0) break;
      }
    }

    // ---- partial MFMAs: 4 chains (one per gate) ----
    f32x4 acc[4];
#pragma unroll
    for (int cg = 0; cg < 4; ++cg) acc[cg] = f32x4{0.f, 0.f, 0.f, 0.f};
#pragma unroll
    for (int cg = 0; cg < 4; ++cg) {
#pragma unroll
      for (int ks = 0; ks < XK; ++ks)
        acc[cg] = __builtin_amdgcn_mfma_f32_16x16x32_bf16(xa[ks], bw[cg][ks], acc[cg], 0, 0, 0);
#pragma unroll
      for (int ks = 0; ks < 4; ++ks)
        acc[cg] = __builtin_amdgcn_mfma_f32_16x16x32_bf16(ha[ks], br[cg][ks], acc[cg], 0, 0, 0);
    }

    // ---- write gate-vec partials (b128) into parity buffer ----
#pragma unroll
    for (int r = 0; r < 4; ++r) {
      f32x4 zv = {acc[0][r], acc[1][r], acc[2][r], acc[3][r]};
      zp[par][w][kq * 4 + r][arow] = zv;
    }
    __syncthreads();   // B1: all partials visible (only barrier per step)

    // ---- wave 0 only: reduce, gates, state, pack, fire-and-forget stores ----
    if (w == 0) {
#pragma unroll
      for (int r = 0; r < 4; ++r) {
        const int row = kq * 4 + r;
        f32x4 s = zp[par][0][row][arow];
        s += zp[par][1][row][arow];
        s += zp[par][2][row][arow];
        s += zp[par][3][row][arow];
        float zi = s[0] + biasv[0];
        float zf = s[1] + biasv[1];
        float zg = s[2] + biasv[2];
        float zo = s[3] + biasv[3];
        cr[r] = sigm(zf) * cr[r] + sigm(zi) * tanh_fast(zg);
        hsm[row][arow] = f2bf(sigm(zo) * tanh_fast(cr[r]));
      }
      // same-wave LDS write->read: ordered by lgkmcnt, no barrier needed
      if (tid < 32) {
        int row = tid >> 1, q = tid & 1;
        uint32_t d0 = (uint16_t)hsm[row][q*8+0] | ((uint32_t)(uint16_t)hsm[row][q*8+1] << 16);
        uint32_t d1 = (uint16_t)hsm[row][q*8+2] | ((uint32_t)(uint16_t)hsm[row][q*8+3] << 16);
        uint32_t d2 = (uint16_t)hsm[row][q*8+4] | ((uint32_t)(uint16_t)hsm[row][q*8+5] << 16);
        uint32_t d3 = (uint16_t)hsm[row][q*8+6] | ((uint32_t)(uint16_t)hsm[row][q*8+7] << 16);
        u32x4 v = {d0, d1, d2, d3};
        st16_wt(Hown + ((size_t)(t + 1) * BATCH + rbase + row) * UU + jbase + q * 8, v);
      }
    }
    // waves 1-3 proceed directly; their next zp write targets parity^1, and
    // their step-t+2 writes sit behind B1(t+1), which wave 0 reaches only
    // after finishing its step-t reads -> no WAR hazard on zp.
  }
}

__global__ __launch_bounds__(256, 1) void lstm_scan(
    const float* __restrict__ inputs,
    const float* __restrict__ W0, const float* __restrict__ R0, const float* __restrict__ b0,
    const float* __restrict__ h0i, const float* __restrict__ c0i,
    const float* __restrict__ W1, const float* __restrict__ R1, const float* __restrict__ b1,
    const float* __restrict__ h1i, const float* __restrict__ c1i,
    const float* __restrict__ W2, const float* __restrict__ R2, const float* __restrict__ b2,
    const float* __restrict__ h2i, const float* __restrict__ c2i,
    short* __restrict__ H0, short* __restrict__ H1, short* __restrict__ H2)
{
  const int layer = blockIdx.x >> 6;    // 0..2
  const int sub   = blockIdx.x & 63;
  const int jblk  = sub & 31;
  const int rbase = (sub >> 5) * 16;

  if (layer == 0)
    scan_body<true >(jblk, rbase, inputs, nullptr, H0, W0, R0, b0, h0i, c0i);
  else if (layer == 1)
    scan_body<false>(jblk, rbase, nullptr, H0, H1, W1, R1, b1, h1i, c1i);
  else
    scan_body<false>(jblk, rbase, nullptr, H1, H2, W2, R2, b2, h2i, c2i);
}

// Y[b][t][:] = H2[t+1][b][:] @ Wd + bd.  Tile: 128 rows x 64 cols per WG.
__global__ __launch_bounds__(256, 2) void dense_out(
    const short* __restrict__ H2,      // [T+1][32][512]
    const float* __restrict__ Wd,      // [512][256]
    const float* __restrict__ bd,      // [256]
    float* __restrict__ out)           // [32][512][256]
{
  const int mblock = blockIdx.x;       // 0..127
  const int nblock = blockIdx.y;       // 0..3
  const int tid  = threadIdx.x;
  const int wave = tid >> 6;
  const int lane = tid & 63;
  const int col  = lane & 15;
  const int kq   = lane >> 4;

  __shared__ short wlds[64][264];

  f32x4 acc[2][4];
#pragma unroll
  for (int mi = 0; mi < 2; ++mi)
#pragma unroll
    for (int ni = 0; ni < 4; ++ni)
      acc[mi][ni] = f32x4{0.f, 0.f, 0.f, 0.f};

  const short* Abase = H2 + (size_t)32 * UU;   // skip init tile

  for (int half = 0; half < 2; ++half) {
    __syncthreads();
    for (int idx = tid; idx < 256 * 64; idx += 256) {
      int k = idx >> 6;
      int c = idx & 63;
      wlds[c][k] = f2bf(Wd[(size_t)(half * 256 + k) * 256 + nblock * 64 + c]);
    }
    __syncthreads();
#pragma unroll
    for (int ks = 0; ks < 8; ++ks) {
      const int d0g = half * 256 + ks * 32 + kq * 8;
      const int d0l = ks * 32 + kq * 8;
      const size_t r0 = (size_t)(mblock * 128 + wave * 32 + col) * UU;
      const size_t r1 = (size_t)(mblock * 128 + wave * 32 + 16 + col) * UU;
      bf16x8 a0 = *(const bf16x8*)(Abase + r0 + d0g);
      bf16x8 a1 = *(const bf16x8*)(Abase + r1 + d0g);
#pragma unroll
      for (int ni = 0; ni < 4; ++ni) {
        bf16x8 bv = *(const bf16x8*)(&wlds[ni * 16 + col][d0l]);
        acc[0][ni] = __builtin_amdgcn_mfma_f32_16x16x32_bf16(a0, bv, acc[0][ni], 0, 0, 0);
        acc[1][ni] = __builtin_amdgcn_mfma_f32_16x16x32_bf16(a1, bv, acc[1][ni], 0, 0, 0);
      }
    }
  }

#pragma unroll
  for (int ni = 0; ni < 4; ++ni) {
    float bdv = bd[nblock * 64 + ni * 16 + col];
#pragma unroll
    for (int mi = 0; mi < 2; ++mi) {
#pragma unroll
      for (int r = 0; r < 4; ++r) {
        int grow = mblock * 128 + wave * 32 + mi * 16 + kq * 4 + r;
        int t = grow >> 5, b = grow & 31;
        out[((size_t)b * SEQT + t) * DIM + nblock * 64 + ni * 16 + col] = acc[mi][ni][r] + bdv;
      }
    }
  }
}

extern "C" void kernel_launch(void* const* d_in, const int* in_sizes, int n_in,
                              void* d_out, int out_size, void* d_ws, size_t ws_size,
                              hipStream_t stream) {
  const float* inputs = (const float*)d_in[0];
  const float* W0 = (const float*)d_in[1];
  const float* R0 = (const float*)d_in[2];
  const float* b0 = (const float*)d_in[3];
  const float* h0 = (const float*)d_in[4];
  const float* c0 = (const float*)d_in[5];
  const float* W1 = (const float*)d_in[6];
  const float* R1 = (const float*)d_in[7];
  const float* b1 = (const float*)d_in[8];
  const float* h1 = (const float*)d_in[9];
  const float* c1 = (const float*)d_in[10];
  const float* W2 = (const float*)d_in[11];
  const float* R2 = (const float*)d_in[12];
  const float* b2 = (const float*)d_in[13];
  const float* h2 = (const float*)d_in[14];
  const float* c2 = (const float*)d_in[15];
  const float* Wd = (const float*)d_in[16];
  const float* bd = (const float*)d_in[17];

  char* base = (char*)d_ws;
  const size_t HX = (size_t)(SEQT + 1) * BATCH * UU * sizeof(short); // ~16.8 MB
  short* H0 = (short*)(base);
  short* H1 = (short*)(base + HX);
  short* H2 = (short*)(base + 2 * HX);

  // re-arm sentinels every launch (replay-safe)
  const size_t n16 = 3 * HX / 16;
  hipLaunchKernelGGL(fill_sent, dim3(2048), dim3(256), 0, stream,
                     (uint32_t*)base, n16);

  hipLaunchKernelGGL(lstm_scan, dim3(192), dim3(256), 0, stream,
                     inputs, W0, R0, b0, h0, c0, W1, R1, b1, h1, c1,
                     W2, R2, b2, h2, c2, H0, H1, H2);

  hipLaunchKernelGGL(dense_out, dim3(128, 4), dim3(256), 0, stream,
                     H2, Wd, bd, (float*)d_out);
}